// Round 5
// baseline (213.842 us; speedup 1.0000x reference)
//
#include <hip/hip_runtime.h>

// Problem constants
#define B_  32
#define C_  64
#define H_  64
#define W_  64
#define O_  128
#define LAT 64
#define HW  (H_*W_)
#define KJ  (O_*C_*9)      // 73728
#define KTOT 576           // C_*9, GEMM K per batch
#define NKS 18             // K steps of 32

typedef __bf16 bf16x8 __attribute__((ext_vector_type(8)));
typedef float  f32x4  __attribute__((ext_vector_type(4)));

// ---------------------------------------------------------------------------
// Stage 1: transpose x -> xT[b][h][w][c] bf16, plus per-(b,h,c) row sums.
// ---------------------------------------------------------------------------
__global__ __launch_bounds__(256) void transpose_gap(const float* __restrict__ x,
                                                     __bf16* __restrict__ xT,
                                                     float* __restrict__ gap_part) {
    int bh = blockIdx.x, b = bh >> 6, h = bh & 63;
    __shared__ float lt[64 * 65];
    int t = threadIdx.x;
    int cc0 = t >> 4, w4 = (t & 15) * 4;

    #pragma unroll
    for (int i = 0; i < 4; i++) {
        int cc = cc0 + 16 * i;
        float4 v = *(const float4*)(x + (((size_t)(b * C_ + cc) * H_) + h) * W_ + w4);
        lt[cc * 65 + w4 + 0] = v.x;
        lt[cc * 65 + w4 + 1] = v.y;
        lt[cc * 65 + w4 + 2] = v.z;
        lt[cc * 65 + w4 + 3] = v.w;
        float s = (v.x + v.y) + (v.z + v.w);
        s += __shfl_xor(s, 1); s += __shfl_xor(s, 2);
        s += __shfl_xor(s, 4); s += __shfl_xor(s, 8);
        if ((t & 15) == 0) gap_part[h * 2048 + b * 64 + cc] = s;
    }
    __syncthreads();

    __bf16* dst = xT + ((size_t)(b * H_ + h) * W_) * C_;
    #pragma unroll
    for (int k = 0; k < 2; k++) {
        int chunk = t + k * 256;
        int w = chunk >> 3, c8 = chunk & 7;
        __bf16 g[8];
        #pragma unroll
        for (int i = 0; i < 8; i++) g[i] = (__bf16)lt[(c8 * 8 + i) * 65 + w];
        *(int4*)(dst + w * C_ + c8 * 8) = *(int4*)g;
    }
}

// ---------------------------------------------------------------------------
// Stage 2+3 fused: gap reduction + 2-layer MLP (in LDS, wave-parallel) +
// kernel generator -> bf16 conv-native layout kbf2[b][ks][o][kk].
// Grid: 256 blocks = (o = bx&127, bhalf = bx>>7), 576 threads.
// Phases 1-3 use threads 0..511 (8 waves; wave w handles batches w and w+8).
// Phase 4: thread t owns Wf column j = o*576+t; f2 read from LDS via
// wave-uniform broadcast loads; LDS shuffle makes global writes coalesced.
// ---------------------------------------------------------------------------
#define KGP2 592
__global__ __launch_bounds__(576) void kergen_fused(const float* __restrict__ gap_part,
                                                    const float* __restrict__ W1,
                                                    const float* __restrict__ b1,
                                                    const float* __restrict__ W2,
                                                    const float* __restrict__ b2,
                                                    const float* __restrict__ Wf,
                                                    const float* __restrict__ bfv,
                                                    __bf16* __restrict__ kbf2) {
    int o = blockIdx.x & 127, b0 = (blockIdx.x >> 7) * 16;
    int t = threadIdx.x;
    __shared__ float gL[16 * 64];     // gap per (bb,c)
    __shared__ float f1L[16 * 64];
    __shared__ float f2T[64 * 16];    // TRANSPOSED: [l][bb] for phase-4 reads
    __shared__ __bf16 ltk[16 * KGP2];

    int bb1 = t >> 6, c = t & 63;     // bb1 in 0..7 for t<512
    // Phase 1: gap reduction (coalesced: lanes sweep c)
    if (t < 512) {
        float s0 = 0.f, s1 = 0.f;
        #pragma unroll 8
        for (int h = 0; h < 64; h++) {
            s0 += gap_part[h * 2048 + (b0 + bb1) * 64 + c];
            s1 += gap_part[h * 2048 + (b0 + 8 + bb1) * 64 + c];
        }
        gL[bb1 * 64 + c] = s0 * (1.0f / (float)HW);
        gL[(bb1 + 8) * 64 + c] = s1 * (1.0f / (float)HW);
    }
    __syncthreads();
    // Phase 2: MLP layer 1 (gL broadcast reads; W1 coalesced, shared by 2 bb)
    if (t < 512) {
        float a1 = b1[c], a2 = a1;
        #pragma unroll 8
        for (int l = 0; l < LAT; l++) {
            float w = W1[l * LAT + c];
            a1 = fmaf(gL[bb1 * 64 + l], w, a1);
            a2 = fmaf(gL[(bb1 + 8) * 64 + l], w, a2);
        }
        f1L[bb1 * 64 + c] = fmaxf(a1, 0.f);
        f1L[(bb1 + 8) * 64 + c] = fmaxf(a2, 0.f);
    }
    __syncthreads();
    // Phase 3: MLP layer 2 -> f2T[l][bb]
    if (t < 512) {
        float a1 = b2[c], a2 = a1;
        #pragma unroll 8
        for (int l = 0; l < LAT; l++) {
            float w = W2[l * LAT + c];
            a1 = fmaf(f1L[bb1 * 64 + l], w, a1);
            a2 = fmaf(f1L[(bb1 + 8) * 64 + l], w, a2);
        }
        f2T[c * 16 + bb1] = fmaxf(a1, 0.f);
        f2T[c * 16 + bb1 + 8] = fmaxf(a2, 0.f);
    }
    __syncthreads();

    // Phase 4: ker[bb][j] = bf[j] + sum_l f2[bb][l] * Wf[l][j]
    int j = o * KTOT + t;
    float acc[16];
    float base = bfv[j];
    #pragma unroll
    for (int i = 0; i < 16; i++) acc[i] = base;

    for (int l8 = 0; l8 < LAT; l8 += 8) {
        float w8[8];
        #pragma unroll
        for (int i = 0; i < 8; i++) w8[i] = Wf[(size_t)(l8 + i) * KJ + j];
        #pragma unroll
        for (int i = 0; i < 8; i++) {
            const float* fp = &f2T[(l8 + i) * 16];   // uniform -> LDS broadcast
            #pragma unroll
            for (int bb = 0; bb < 16; bb++)
                acc[bb] = fmaf(fp[bb], w8[i], acc[bb]);
        }
    }

    int cc = t / 9, tap = t - cc * 9;
    int tpp = (tap * 2 + (cc >> 5)) * 32 + (cc & 31);
    #pragma unroll
    for (int bb = 0; bb < 16; bb++) ltk[bb * KGP2 + tpp] = (__bf16)acc[bb];
    __syncthreads();
    #pragma unroll
    for (int bb = 0; bb < 16; bb++) {
        int ks = t >> 5;
        kbf2[(((size_t)(b0 + bb) * NKS + ks) * O_ + o) * 32 + (t & 31)] =
            ltk[bb * KGP2 + t];
    }
}

// ---------------------------------------------------------------------------
// Stage 4: implicit-GEMM MFMA conv. M=128 o, N=128 px (2 rows), K=576.
// Persistent grid of 768 blocks (exactly 3/CU at (256,3)) looping over the
// 1024 (b, h-tile) tiles -> no scheduling tail; loop-top barrier lets the
// previous tile's epilogue overlap next tile's staging.
// Depth-3 register prefetch of A (4-buffer rotation): consume lands ~3
// k-steps (~240 cyc) after issue -> L2 latency hidden.
// VGPR budget at (256,3) = 170: 64 acc + 64 Abuf + ~35 misc fits (round-3
// lesson: overflow -> scratch spill shows as WRITE_SIZE blowup).
// ---------------------------------------------------------------------------
#define CPAD 72
#define ROWE (66 * CPAD)

__global__ __launch_bounds__(256, 3) void conv_mfma(const __bf16* __restrict__ xT,
                                                    const __bf16* __restrict__ kbf2,
                                                    float* __restrict__ out) {
    __shared__ __bf16 xs[4 * ROWE];
    int tid = threadIdx.x;
    int wave = tid >> 6, lane = tid & 63;
    int wi = wave >> 1, wj = wave & 1;
    int l15 = lane & 15, quad = lane >> 4;

    for (int tile = blockIdx.x; tile < 1024; tile += 768) {
        int b = tile >> 5, bx = tile & 31;
        int htile = (bx & 7) * 4 + (bx >> 3);      // XCD-local h grouping
        int h0 = htile * 2;

        const __bf16* kbA = kbf2 + (size_t)b * (NKS * O_ * 32);
        int mrow = wi * 64 + l15;

        __syncthreads();   // previous tile's xs readers are done

        // A prefetch: k-steps 0..2 (independent of LDS; issue first)
        bf16x8 Abuf[4][4];
        #pragma unroll
        for (int d = 0; d < 3; d++)
            #pragma unroll
            for (int mt = 0; mt < 4; mt++)
                Abuf[d][mt] = *(const bf16x8*)(kbA + d * (O_ * 32) +
                                               (mrow + mt * 16) * 32 + quad * 8);

        // zero halo columns w'=0 and w'=65
        if (tid < 64) {
            int r = tid >> 4, which = (tid >> 3) & 1, c8 = tid & 7;
            *(int4*)(xs + (r * 66 + which * 65) * CPAD + c8 * 8) = int4{0, 0, 0, 0};
        }
        // zero OOB rows (edge tiles only)
        if (h0 == 0) {
            for (int i = tid; i < ROWE / 8; i += 256)
                *(int4*)(xs + i * 8) = int4{0, 0, 0, 0};
        }
        if (h0 == H_ - 2) {
            for (int i = tid; i < ROWE / 8; i += 256)
                *(int4*)(xs + 3 * ROWE + i * 8) = int4{0, 0, 0, 0};
        }
        // stage rows h0-1 .. h0+2
        #pragma unroll
        for (int i = 0; i < 8; i++) {
            int chunk = tid + i * 256;
            int c8 = chunk & 7, w = (chunk >> 3) & 63, r = chunk >> 9;
            int hh = h0 - 1 + r;
            if ((unsigned)hh < (unsigned)H_) {
                int4 v = *(const int4*)(xT + ((size_t)(b * H_ + hh) * W_ + w) * C_ + c8 * 8);
                *(int4*)(xs + (r * 66 + w + 1) * CPAD + c8 * 8) = v;
            }
        }
        __syncthreads();

        f32x4 acc[4][4];
        #pragma unroll
        for (int mt = 0; mt < 4; mt++)
            #pragma unroll
            for (int nt = 0; nt < 4; nt++)
                acc[mt][nt] = (f32x4){0.f, 0.f, 0.f, 0.f};

        #pragma unroll
        for (int ks = 0; ks < NKS; ks++) {
            if (ks < NKS - 3) {
                #pragma unroll
                for (int mt = 0; mt < 4; mt++)
                    Abuf[(ks + 3) & 3][mt] =
                        *(const bf16x8*)(kbA + (ks + 3) * (O_ * 32) +
                                         (mrow + mt * 16) * 32 + quad * 8);
            }
            int tap = ks >> 1;                     // compile-time after unroll
            int kh = tap / 3, kw = tap - kh * 3;
            int c0 = (ks & 1) * 32;
            const __bf16* Bb = xs + ((wj + kh) * 66 + kw + l15) * CPAD + c0 + quad * 8;
            #pragma unroll
            for (int nt = 0; nt < 4; nt++) {
                bf16x8 bfrag = *(const bf16x8*)(Bb + nt * 16 * CPAD);
                #pragma unroll
                for (int mt = 0; mt < 4; mt++)
                    acc[mt][nt] = __builtin_amdgcn_mfma_f32_16x16x32_bf16(
                        Abuf[ks & 3][mt], bfrag, acc[mt][nt], 0, 0, 0);
            }
        }

        // epilogue: D row = quad*4 + reg, col = l15
        int h = h0 + wj;
        float* ob = out + ((size_t)b * O_ + wi * 64) * HW + h * W_;
        #pragma unroll
        for (int mt = 0; mt < 4; mt++) {
            #pragma unroll
            for (int nt = 0; nt < 4; nt++) {
                int w = nt * 16 + l15;
                #pragma unroll
                for (int r = 0; r < 4; r++) {
                    int oo = mt * 16 + quad * 4 + r;
                    ob[(size_t)oo * HW + w] = acc[mt][nt][r];
                }
            }
        }
    }
}

// ---------------------------------------------------------------------------
// Launch (3 kernels)
// ---------------------------------------------------------------------------
extern "C" void kernel_launch(void* const* d_in, const int* in_sizes, int n_in,
                              void* d_out, int out_size, void* d_ws, size_t ws_size,
                              hipStream_t stream) {
    const float* x  = (const float*)d_in[0];
    const float* W1 = (const float*)d_in[1];
    const float* b1 = (const float*)d_in[2];
    const float* W2 = (const float*)d_in[3];
    const float* b2 = (const float*)d_in[4];
    const float* Wf = (const float*)d_in[5];
    const float* bf = (const float*)d_in[6];
    float* out = (float*)d_out;

    // Workspace layout:
    //   gap_part : 64*32*64 f32      @ 0          (512 KB)
    //   kbf2     : 32*18*128*32 bf16 @ 512 KB     (4.72 MB)
    //   xT       : 32*64*64*64 bf16  @ 5.24 MB    (16.8 MB)
    float*  gap_part = (float*)d_ws;
    __bf16* kbf2     = (__bf16*)((char*)d_ws + 524288);
    __bf16* xT       = (__bf16*)((char*)d_ws + 524288 + (size_t)B_ * NKS * O_ * 32 * 2);

    transpose_gap<<<B_ * H_, 256, 0, stream>>>(x, xT, gap_part);
    kergen_fused<<<256, 576, 0, stream>>>(gap_part, W1, b1, W2, b2, Wf, bf, kbf2);
    conv_mfma<<<768, 256, 0, stream>>>(xT, kbf2, out);
}

// Round 6
// 165.688 us; speedup vs baseline: 1.2906x; 1.2906x over previous
//
#include <hip/hip_runtime.h>

// Problem constants
#define B_  32
#define C_  64
#define H_  64
#define W_  64
#define O_  128
#define LAT 64
#define HW  (H_*W_)
#define KJ  (O_*C_*9)      // 73728
#define KTOT 576           // C_*9, GEMM K per batch
#define NKS 18             // K steps of 32

typedef __bf16 bf16x8 __attribute__((ext_vector_type(8)));
typedef float  f32x4  __attribute__((ext_vector_type(4)));

// ---------------------------------------------------------------------------
// Stage 1: transpose x -> xT[b][h][w][c] bf16, plus per-(b,h,c) row sums.
// ---------------------------------------------------------------------------
__global__ __launch_bounds__(256) void transpose_gap(const float* __restrict__ x,
                                                     __bf16* __restrict__ xT,
                                                     float* __restrict__ gap_part) {
    int bh = blockIdx.x, b = bh >> 6, h = bh & 63;
    __shared__ float lt[64 * 65];
    int t = threadIdx.x;
    int cc0 = t >> 4, w4 = (t & 15) * 4;

    #pragma unroll
    for (int i = 0; i < 4; i++) {
        int cc = cc0 + 16 * i;
        float4 v = *(const float4*)(x + (((size_t)(b * C_ + cc) * H_) + h) * W_ + w4);
        lt[cc * 65 + w4 + 0] = v.x;
        lt[cc * 65 + w4 + 1] = v.y;
        lt[cc * 65 + w4 + 2] = v.z;
        lt[cc * 65 + w4 + 3] = v.w;
        float s = (v.x + v.y) + (v.z + v.w);
        s += __shfl_xor(s, 1); s += __shfl_xor(s, 2);
        s += __shfl_xor(s, 4); s += __shfl_xor(s, 8);
        if ((t & 15) == 0) gap_part[h * 2048 + b * 64 + cc] = s;
    }
    __syncthreads();

    __bf16* dst = xT + ((size_t)(b * H_ + h) * W_) * C_;
    #pragma unroll
    for (int k = 0; k < 2; k++) {
        int chunk = t + k * 256;
        int w = chunk >> 3, c8 = chunk & 7;
        __bf16 g[8];
        #pragma unroll
        for (int i = 0; i < 8; i++) g[i] = (__bf16)lt[(c8 * 8 + i) * 65 + w];
        *(int4*)(dst + w * C_ + c8 * 8) = *(int4*)g;
    }
}

// ---------------------------------------------------------------------------
// Stage 2: gap reduction + MLP. Writes f2 transposed: f2t[l][b].
// ---------------------------------------------------------------------------
__global__ __launch_bounds__(64) void mlp_kernel(const float* __restrict__ gap_part,
                                                 const float* __restrict__ W1,
                                                 const float* __restrict__ b1,
                                                 const float* __restrict__ W2,
                                                 const float* __restrict__ b2,
                                                 float* __restrict__ f2t) {
    int b = blockIdx.x, j = threadIdx.x;
    float s = 0.f;
    #pragma unroll 16
    for (int h = 0; h < 64; h++) s += gap_part[h * 2048 + b * 64 + j];
    __shared__ float g[LAT], f1[LAT];
    g[j] = s * (1.0f / (float)HW);
    __syncthreads();
    float acc = b1[j];
    #pragma unroll 8
    for (int l = 0; l < LAT; l++) acc = fmaf(g[l], W1[l * LAT + j], acc);
    f1[j] = fmaxf(acc, 0.f);
    __syncthreads();
    float acc2 = b2[j];
    #pragma unroll 8
    for (int l = 0; l < LAT; l++) acc2 = fmaf(f1[l], W2[l * LAT + j], acc2);
    f2t[j * B_ + b] = fmaxf(acc2, 0.f);
}

// ---------------------------------------------------------------------------
// Stage 3: kernel generator -> bf16, conv-native layout kbf2[b][ks][o][kk].
// (round-4 version: separate from mlp; the round-5 fusion cost +23 us via
// 67 MB of per-block gap_part re-reads)
// ---------------------------------------------------------------------------
#define KGP2 592
__global__ __launch_bounds__(576) void kergen_kernel(const float* __restrict__ f2t,
                                                     const float* __restrict__ Wf,
                                                     const float* __restrict__ bfv,
                                                     __bf16* __restrict__ kbf2) {
    int o = blockIdx.x & 127, b0 = (blockIdx.x >> 7) * 16;
    int t = threadIdx.x;
    __shared__ __bf16 ltk[16 * KGP2];

    int j = o * KTOT + t;
    float acc[16];
    float base = bfv[j];
    #pragma unroll
    for (int i = 0; i < 16; i++) acc[i] = base;

    for (int l8 = 0; l8 < LAT; l8 += 8) {
        float w8[8];
        #pragma unroll
        for (int i = 0; i < 8; i++) w8[i] = Wf[(size_t)(l8 + i) * KJ + j];
        #pragma unroll
        for (int i = 0; i < 8; i++) {
            #pragma unroll
            for (int bb = 0; bb < 16; bb++)
                acc[bb] = fmaf(f2t[(l8 + i) * B_ + b0 + bb], w8[i], acc[bb]);
        }
    }

    int c = t / 9, tap = t - c * 9;
    int tpp = (tap * 2 + (c >> 5)) * 32 + (c & 31);
    #pragma unroll
    for (int bb = 0; bb < 16; bb++) ltk[bb * KGP2 + tpp] = (__bf16)acc[bb];
    __syncthreads();
    int ks = t >> 5, kk = t & 31;
    #pragma unroll
    for (int bb = 0; bb < 16; bb++)
        kbf2[(((size_t)(b0 + bb) * NKS + ks) * O_ + o) * 32 + kk] = ltk[bb * KGP2 + t];
}

// ---------------------------------------------------------------------------
// Stage 4: implicit-GEMM MFMA conv. M=128 o, N=256 px (4 rows), K=576.
// Grid 512 blocks = exactly 2/CU at (256,2): no scheduling tail.
// Per wave k-step: 4 A global loads + 8 B ds_reads + 32 MFMA (2x the
// MFMA:latency ratio of the N=128 tile; A traffic halves to ~150 MB).
// Regs: 128 acc + 48 Abuf + ~35 misc ~= 210 <= 256 cap -> no spill
// (round-3/5 lesson: overflow shows as WRITE_SIZE blowup).
// A prefetch issued AFTER staging barrier (round-5 lesson: issuing it
// before staging makes Abuf+staging temps co-live -> spill).
// CPAD=76: l15 lane stride 38 dwords -> conflict-free ds_read_b128.
// ---------------------------------------------------------------------------
#define CPAD 76
#define RSTRIDE (66 * CPAD)

__global__ __launch_bounds__(256, 2) void conv_mfma(const __bf16* __restrict__ xT,
                                                    const __bf16* __restrict__ kbf2,
                                                    float* __restrict__ out) {
    int b  = blockIdx.y;
    int bx = blockIdx.x;                        // 0..15
    int htile = ((bx & 7) << 1) | (bx >> 3);    // XCD-local h grouping
    int h0 = htile * 4;
    __shared__ __bf16 xs[6 * RSTRIDE];          // 60192 B
    int tid = threadIdx.x;

    // zero halo columns w'=0 and w'=65 for 6 rows
    if (tid < 96) {
        int r = tid >> 4, which = (tid >> 3) & 1, c8 = tid & 7;
        *(int4*)(xs + (r * 66 + which * 65) * CPAD + c8 * 8) = int4{0, 0, 0, 0};
    }
    // zero OOB rows (edge tiles only; RSTRIDE/8 = 627)
    if (h0 == 0) {
        for (int i = tid; i < RSTRIDE / 8; i += 256)
            *(int4*)(xs + i * 8) = int4{0, 0, 0, 0};
    }
    if (h0 == H_ - 4) {
        for (int i = tid; i < RSTRIDE / 8; i += 256)
            *(int4*)(xs + 5 * RSTRIDE + i * 8) = int4{0, 0, 0, 0};
    }
    // stage rows h0-1 .. h0+4 (3072 16B chunks, coalesced)
    #pragma unroll
    for (int i = 0; i < 12; i++) {
        int chunk = tid + i * 256;
        int c8 = chunk & 7, w = (chunk >> 3) & 63, r = chunk >> 9;
        int hh = h0 - 1 + r;
        if ((unsigned)hh < (unsigned)H_) {
            int4 v = *(const int4*)(xT + ((size_t)(b * H_ + hh) * W_ + w) * C_ + c8 * 8);
            *(int4*)(xs + (r * 66 + w + 1) * CPAD + c8 * 8) = v;
        }
    }
    __syncthreads();

    int wave = tid >> 6, lane = tid & 63;
    int wi = wave >> 1, wj = wave & 1;          // wi: M-half, wj: row-pair
    int l15 = lane & 15, quad = lane >> 4;

    const __bf16* kbA = kbf2 + (size_t)b * (NKS * O_ * 32);
    int mrow = wi * 64 + l15;

    f32x4 acc[4][8];
    #pragma unroll
    for (int mt = 0; mt < 4; mt++)
        #pragma unroll
        for (int nt = 0; nt < 8; nt++)
            acc[mt][nt] = (f32x4){0.f, 0.f, 0.f, 0.f};

    bf16x8 Abuf[3][4];
    #pragma unroll
    for (int d = 0; d < 2; d++)
        #pragma unroll
        for (int mt = 0; mt < 4; mt++)
            Abuf[d][mt] = *(const bf16x8*)(kbA + d * (O_ * 32) +
                                           (mrow + mt * 16) * 32 + quad * 8);

    #pragma unroll
    for (int ks = 0; ks < NKS; ks++) {
        if (ks < NKS - 2) {
            #pragma unroll
            for (int mt = 0; mt < 4; mt++)
                Abuf[(ks + 2) % 3][mt] =
                    *(const bf16x8*)(kbA + (ks + 2) * (O_ * 32) +
                                     (mrow + mt * 16) * 32 + quad * 8);
        }
        int tap = ks >> 1;                      // compile-time after unroll
        int kh = tap / 3, kw = tap - kh * 3;
        int c0 = (ks & 1) * 32;
        #pragma unroll
        for (int nt = 0; nt < 8; nt++) {
            int rin = wj * 2 + (nt >> 2) + kh;          // 0..5
            int wcol = (nt & 3) * 16 + l15 + kw;        // 0..65
            bf16x8 bfrag = *(const bf16x8*)(xs + (rin * 66 + wcol) * CPAD +
                                            c0 + quad * 8);
            #pragma unroll
            for (int mt = 0; mt < 4; mt++)
                acc[mt][nt] = __builtin_amdgcn_mfma_f32_16x16x32_bf16(
                    Abuf[ks % 3][mt], bfrag, acc[mt][nt], 0, 0, 0);
        }
    }

    // epilogue: D row (o) = quad*4 + reg, col (px) = l15
    float* ob = out + ((size_t)b * O_ + wi * 64) * HW;
    #pragma unroll
    for (int mt = 0; mt < 4; mt++) {
        #pragma unroll
        for (int nt = 0; nt < 8; nt++) {
            int h = h0 + wj * 2 + (nt >> 2);
            int w = (nt & 3) * 16 + l15;
            #pragma unroll
            for (int r = 0; r < 4; r++) {
                int oo = mt * 16 + quad * 4 + r;
                ob[(size_t)oo * HW + h * W_ + w] = acc[mt][nt][r];
            }
        }
    }
}

// ---------------------------------------------------------------------------
// Launch (4 kernels)
// ---------------------------------------------------------------------------
extern "C" void kernel_launch(void* const* d_in, const int* in_sizes, int n_in,
                              void* d_out, int out_size, void* d_ws, size_t ws_size,
                              hipStream_t stream) {
    const float* x  = (const float*)d_in[0];
    const float* W1 = (const float*)d_in[1];
    const float* b1 = (const float*)d_in[2];
    const float* W2 = (const float*)d_in[3];
    const float* b2 = (const float*)d_in[4];
    const float* Wf = (const float*)d_in[5];
    const float* bf = (const float*)d_in[6];
    float* out = (float*)d_out;

    // Workspace layout:
    //   gap_part : 64*32*64 f32      @ 0          (512 KB)
    //   f2t      : 64*32 f32         @ 512 KB     (8 KB)
    //   kbf2     : 32*18*128*32 bf16 @ 528 KB     (4.72 MB)
    //   xT       : 32*64*64*64 bf16  @ ~5.25 MB   (16.8 MB)
    float*  gap_part = (float*)d_ws;
    float*  f2t      = (float*)((char*)d_ws + 524288);
    __bf16* kbf2     = (__bf16*)((char*)d_ws + 540672);
    __bf16* xT       = (__bf16*)((char*)d_ws + 540672 + (size_t)B_ * NKS * O_ * 32 * 2);

    transpose_gap<<<B_ * H_, 256, 0, stream>>>(x, xT, gap_part);
    mlp_kernel<<<B_, 64, 0, stream>>>(gap_part, W1, b1, W2, b2, f2t);
    kergen_kernel<<<256, 576, 0, stream>>>(f2t, Wf, bf, kbf2);
    conv_mfma<<<dim3(16, B_), 256, 0, stream>>>(xT, kbf2, out);
}